// Round 13
// baseline (210.138 us; speedup 1.0000x reference)
//
#include <hip/hip_runtime.h>
#include <hip/hip_bf16.h>
#include <math.h>

#define N_NODES 50000
#define N_EDGES 1600000
#define IN_DIM  128
#define HID     64
#define EPB     4096   // edges per sort block
#define NBLK    391    // ceil(N_EDGES / EPB)
#define NB      391    // ceil(N_NODES / 128) buckets of 128 nodes
#define CAP     8192   // LDS staging capacity (edges/bucket; mean 4092)
#define PBKT    8192   // padded per-bucket arena in csr_pad (max ~5300 used)
#define GEMM0G  782    // layer-0 GEMM blocks
#define TSTAGE  2048   // staged idx entries per 16-node tile (mean ~580)
static constexpr float EPS = 1e-6f;

typedef __attribute__((ext_vector_type(8))) short          short8;   // 8 bf16
typedef __attribute__((ext_vector_type(4))) int            i32x4;
typedef __attribute__((ext_vector_type(4))) float          f32x4;
typedef __attribute__((ext_vector_type(2))) float          f32x2;

__device__ __forceinline__ unsigned short f2bf(float f) {   // round-nearest-even
    union { float f; unsigned int i; } c; c.f = f;
    unsigned int r = c.i + 0x7FFFu + ((c.i >> 16) & 1u);
    return (unsigned short)(r >> 16);
}
__device__ __forceinline__ unsigned char f2fp8(float f) {   // OCP e4m3, HW cvt
    int p = __builtin_amdgcn_cvt_pk_fp8_f32(f, f, 0, false);
    return (unsigned char)(p & 0xff);
}

// ==== weight packing =========================================================

template <int K>
__device__ __forceinline__ void pack_body(const float* __restrict__ wS,
                                          const float* __restrict__ wN,
                                          unsigned short* __restrict__ pS,
                                          unsigned short* __restrict__ pN, int blk) {
    constexpr int NSLOT = (K / 32) * 4 * 64;
    int slot = blk * 256 + (int)threadIdx.x;
    if (slot >= NSLOT) return;
    int lane = slot & 63;
    int ct   = slot >> 6;
    int t    = ct & 3;
    int c    = ct >> 2;
    int m    = lane & 15;
    int quad = lane >> 4;
    int col  = t * 16 + m;
#pragma unroll
    for (int j = 0; j < 8; ++j) {
        int k = c * 32 + quad * 8 + j;
        pS[slot * 8 + j] = f2bf(wS[k * 64 + col]);
        pN[slot * 8 + j] = f2bf(wN[k * 64 + col]);
    }
}

// ==== dual GEMM body (layer 0) ===============================================
template <int K, bool F32IN>
__device__ __forceinline__ void gemm_body(
    const void* __restrict__ Av,
    const unsigned short* __restrict__ pS,
    const unsigned short* __restrict__ pN,
    float* __restrict__ hs, unsigned char* __restrict__ hnq, int blk) {
    constexpr int NC = K / 32;
    int lane = threadIdx.x & 63;
    int wv   = threadIdx.x >> 6;
    int tile = blk * 4 + wv;
    if (tile >= N_NODES / 16) return;
    int m    = lane & 15;
    int quad = lane >> 4;

    const short8* pSf = (const short8*)pS;
    const short8* pNf = (const short8*)pN;

    f32x4 accS[4], accN[4];
#pragma unroll
    for (int t = 0; t < 4; ++t) {
        accS[t] = (f32x4){0.f, 0.f, 0.f, 0.f};
        accN[t] = (f32x4){0.f, 0.f, 0.f, 0.f};
    }
#pragma unroll
    for (int c = 0; c < NC; ++c) {
        short8 a;
        if constexpr (F32IN) {
            const float* Af = (const float*)Av + ((size_t)tile * 16 + m) * K + quad * 8 + c * 32;
            f32x4 a0 = *(const f32x4*)Af;
            f32x4 a1 = *(const f32x4*)(Af + 4);
#pragma unroll
            for (int k = 0; k < 4; ++k) a[k]     = (short)f2bf(a0[k]);
#pragma unroll
            for (int k = 0; k < 4; ++k) a[k + 4] = (short)f2bf(a1[k]);
        } else {
            const short8* Af = (const short8*)((const unsigned short*)Av +
                               ((size_t)tile * 16 + m) * K + quad * 8);
            a = Af[c * 4];
        }
#pragma unroll
        for (int t = 0; t < 4; ++t) {
            short8 bs = pSf[(c * 4 + t) * 64 + lane];
            short8 bn = pNf[(c * 4 + t) * 64 + lane];
            accS[t] = __builtin_amdgcn_mfma_f32_16x16x32_bf16(a, bs, accS[t], 0, 0, 0);
            accN[t] = __builtin_amdgcn_mfma_f32_16x16x32_bf16(a, bn, accN[t], 0, 0, 0);
        }
    }
    int row0 = tile * 16 + quad * 4;
#pragma unroll
    for (int t = 0; t < 4; ++t) {
#pragma unroll
        for (int r = 0; r < 4; ++r) {
            size_t o = (size_t)(row0 + r) * HID + t * 16 + m;
            hs[o]  = accS[t][r];
            hnq[o] = f2fp8(accN[t][r]);
        }
    }
}

// ==== kernel 1: histogram count ∥ weight pack ================================
__global__ __launch_bounds__(256) void bucket_count_pack(
    const int* __restrict__ ei, int* __restrict__ bc,
    const float* __restrict__ w0s, const float* __restrict__ w0n,
    const float* __restrict__ w1s, const float* __restrict__ w1n,
    const float* __restrict__ w2s, const float* __restrict__ w2n,
    unsigned short* __restrict__ p0S, unsigned short* __restrict__ p0N,
    unsigned short* __restrict__ p1S, unsigned short* __restrict__ p1N,
    unsigned short* __restrict__ p2S, unsigned short* __restrict__ p2N,
    unsigned char* __restrict__ hnqA, unsigned char* __restrict__ hnqB,
    int* __restrict__ gcount) {
    if (blockIdx.x >= NBLK) {
        int blk = blockIdx.x - NBLK;
        if (blk == 7) {
            if (threadIdx.x >= 128 && threadIdx.x < 144)
                ((unsigned int*)(hnqA + (size_t)N_NODES * HID))[threadIdx.x - 128] = 0u;
            if (threadIdx.x >= 144 && threadIdx.x < 160)
                ((unsigned int*)(hnqB + (size_t)N_NODES * HID))[threadIdx.x - 144] = 0u;
            if (threadIdx.x == 160) gcount[0] = 0;
        }
        if (blk < 4)      pack_body<IN_DIM>(w0s, w0n, p0S, p0N, blk);
        else if (blk < 6) pack_body<HID>(w1s, w1n, p1S, p1N, blk - 4);
        else              pack_body<HID>(w2s, w2n, p2S, p2N, blk - 6);
        return;
    }
    __shared__ int hist[NB];
    for (int i = threadIdx.x; i < NB; i += 256) hist[i] = 0;
    __syncthreads();
    int base = blockIdx.x * EPB;
    int lim  = min(EPB, N_EDGES - base);
    for (int i = threadIdx.x; i < lim; i += 256)
        atomicAdd(&hist[ei[N_EDGES + base + i] >> 7], 1);
    __syncthreads();
    for (int b = threadIdx.x; b < NB; b += 256)
        bc[blockIdx.x * NB + b] = hist[b];
}

// ==== kernel 2: fused col_sum + base-alloc + in-row prefix ∥ layer-0 GEMM ====
__global__ __launch_bounds__(256) void col_sumfix_gemm0(
    int* __restrict__ bc, int* __restrict__ bucketBase, int* __restrict__ bucketTot,
    int* __restrict__ gcount,
    const float* __restrict__ x,
    const unsigned short* __restrict__ p0S, const unsigned short* __restrict__ p0N,
    float* __restrict__ hs, unsigned char* __restrict__ hnq) {
    if (blockIdx.x >= NB) {
        gemm_body<IN_DIM, true>(x, p0S, p0N, hs, hnq, blockIdx.x - NB);
        return;
    }
    __shared__ int vals[NBLK];
    int b = blockIdx.x;
    for (int i = threadIdx.x; i < NBLK; i += 256) vals[i] = bc[i * NB + b];
    __syncthreads();
    if (threadIdx.x < 64) {
        int lane = threadIdx.x;
        int s = 0;
        for (int i = lane; i < NBLK; i += 64) s += vals[i];
#pragma unroll
        for (int off = 32; off >= 1; off >>= 1) s += __shfl_xor(s, off, 64);
        int base = 0;
        if (lane == 0) {
            base = atomicAdd(gcount, s);
            bucketBase[b] = base;
            bucketTot[b]  = s;
        }
        base = __shfl(base, 0, 64);
        int carry = base;
        for (int bs = 0; bs < NBLK; bs += 64) {
            int i = bs + lane;
            int v = (i < NBLK) ? vals[i] : 0;
            int incl = v;
#pragma unroll
            for (int off = 1; off < 64; off <<= 1) {
                int t = __shfl_up(incl, off, 64);
                if (lane >= off) incl += t;
            }
            if (i < NBLK) vals[i] = carry + incl - v;
            carry += __shfl(incl, 63, 64);
        }
    }
    __syncthreads();
    for (int i = threadIdx.x; i < NBLK; i += 256) bc[i * NB + b] = vals[i];
}

// ==== kernel 3: scatter edges into bucket-sorted order =======================
__global__ __launch_bounds__(256) void bucket_scatter(const int* __restrict__ ei,
                                                      const int* __restrict__ bc,
                                                      unsigned int* __restrict__ bucketPacked) {
    __shared__ int cur[NB];
    for (int b = threadIdx.x; b < NB; b += 256)
        cur[b] = bc[blockIdx.x * NB + b];
    __syncthreads();
    int base = blockIdx.x * EPB;
    int lim  = min(EPB, N_EDGES - base);
    for (int i = threadIdx.x; i < lim; i += 256) {
        int s = ei[base + i];
        int d = ei[N_EDGES + base + i];
        int pos = atomicAdd(&cur[d >> 7], 1);
        bucketPacked[pos] = ((unsigned int)s << 7) | (unsigned int)(d & 127);
    }
}

// ==== kernel 4: per-bucket degree count -> padded scan -> pbeg/rdeg ->
// sentinel fill -> local scatter. csr_pad entries are PRE-SHIFTED byte
// offsets (src*64) so the gather loop needs no per-edge shift.
__global__ __launch_bounds__(256) void node_scan_scatter_pad(
    const unsigned int* __restrict__ bucketPacked,
    const int* __restrict__ bucketBase, const int* __restrict__ bucketTot,
    int* __restrict__ pbeg, int* __restrict__ rdeg, int* __restrict__ csr_pad) {
    __shared__ int cnt[128];
    __shared__ int half0;
    __shared__ unsigned int stage[CAP];
    int tid = threadIdx.x;
    if (tid < 128) cnt[tid] = 0;
    __syncthreads();
    int beg = bucketBase[blockIdx.x];
    int n   = bucketTot[blockIdx.x];
    for (int i = tid; i < n; i += 256) {
        unsigned int e = bucketPacked[beg + i];
        if (i < CAP) stage[i] = e;
        atomicAdd(&cnt[e & 127], 1);
    }
    __syncthreads();
    int lane = tid & 63;
    int v    = (tid < 128) ? cnt[tid] : 0;   // raw degree of node tid
    int vp   = (v + 7) & ~7;                 // padded degree
    int incl = vp;
#pragma unroll
    for (int off = 1; off < 64; off <<= 1) {
        int t = __shfl_up(incl, off, 64);
        if (lane >= off) incl += t;
    }
    if (tid == 63) half0 = incl;
    __syncthreads();
    int start = blockIdx.x * PBKT + ((tid >= 64 && tid < 128) ? half0 : 0) + incl - vp;
    int node  = blockIdx.x * 128 + tid;
    if (tid < 128 && node < N_NODES) {
        pbeg[node] = start;
        rdeg[node] = v;
        for (int j = v; j < vp; ++j) csr_pad[start + j] = N_NODES << 6;   // sentinels
        cnt[tid] = start;   // becomes the scatter cursor
    }
    __syncthreads();
    for (int i = tid; i < n; i += 256) {
        unsigned int e = (i < CAP) ? stage[i] : bucketPacked[beg + i];
        int pos = atomicAdd(&cnt[e & 127], 1);
        csr_pad[pos] = (int)((e >> 7) << 6);   // pre-shifted byte offset
    }
}

// ==== fused gather-aggregate + update + NEXT-LAYER dual GEMM (or MLP head) ===
// 4 nodes per wave, 16 lanes per node. Round-18: the tile's CONTIGUOUS csr
// segment (16 nodes allocated in order) is staged into LDS once (coalesced),
// so inner-loop idx loads are ds_read_b128 — off the vmcnt queue, ~1/3 the
// latency; the vmem pipe carries only data gathers. Entries are pre-shifted
// byte offsets. Fallback to global idx reads if the tile overflows TSTAGE.
template <bool MLP>
__global__ __launch_bounds__(256) void agg_update(
    const int* __restrict__ pbeg, const int* __restrict__ rdeg,
    const int* __restrict__ csr_pad,
    const unsigned char* __restrict__ hnq, const float* __restrict__ hs,
    const unsigned short* __restrict__ pS, const unsigned short* __restrict__ pN,
    float* __restrict__ hs2, unsigned char* __restrict__ hnq2,
    const float* __restrict__ mw1, const float* __restrict__ mb1,
    const float* __restrict__ mw2, const float* __restrict__ mb2,
    float* __restrict__ out) {
    __shared__ int sIdx[TSTAGE];
    __shared__ unsigned short sA[MLP ? 1 : 16 * 80];   // 16 nodes x 64 bf16, stride 80
    __shared__ float sW1[MLP ? HID * 32 : 1];
    __shared__ float sW2[MLP ? 32 : 1];
    __shared__ float sB1[MLP ? 32 : 1];
    __shared__ float sH[MLP ? 16 * 68 : 1];
    if (MLP) {
        for (int i = threadIdx.x; i < HID * 32; i += 256) sW1[i] = mw1[i];
        if (threadIdx.x < 32) { sW2[threadIdx.x] = mw2[threadIdx.x]; sB1[threadIdx.x] = mb1[threadIdx.x]; }
    }
    int sn   = threadIdx.x >> 4;          // node slot within block, 0..15
    int r    = threadIdx.x & 15;          // 4B chunk of the 64B row
    int node = blockIdx.x * 16 + sn;      // grid = 3125 -> exactly N_NODES
    // ---- stage the tile's contiguous idx segment ----
    int node0 = blockIdx.x * 16;
    int tbeg  = pbeg[node0];
    int tend  = pbeg[node0 + 15] + ((rdeg[node0 + 15] + 7) & ~7);
    int nstage = min(tend - tbeg, TSTAGE);
    for (int i = threadIdx.x; i < nstage; i += 256) sIdx[i] = csr_pad[tbeg + i];
    __syncthreads();

    int beg  = pbeg[node];
    int dg   = rdeg[node];
    f32x4 h  = *(const f32x4*)(hs + (size_t)node * HID + r * 4);   // prefetch
    int nbat = (dg + 7) >> 3;
    int local = beg - tbeg;
    bool useL = (local + nbat * 8) <= nstage;   // virtually always true
    const unsigned char* hnqr = hnq + r * 4;

    f32x2 acc2[2];
    acc2[0] = (f32x2){0.f, 0.f};
    acc2[1] = (f32x2){0.f, 0.f};

#define AGG_LOOP(IP)                                                          \
    _Pragma("unroll 2")                                                       \
    for (int t = 0; t < nbat; ++t) {                                          \
        i32x4 a = (IP)[2 * t];                                                \
        i32x4 b = (IP)[2 * t + 1];                                            \
        unsigned wv[8];                                                       \
        _Pragma("unroll")                                                     \
        for (int u = 0; u < 4; ++u)                                           \
            wv[u]     = *(const unsigned*)(hnqr + (unsigned)a[u]);            \
        _Pragma("unroll")                                                     \
        for (int u = 0; u < 4; ++u)                                           \
            wv[u + 4] = *(const unsigned*)(hnqr + (unsigned)b[u]);            \
        _Pragma("unroll")                                                     \
        for (int u = 0; u < 8; ++u) {                                         \
            acc2[0] += __builtin_amdgcn_cvt_pk_f32_fp8((int)wv[u], false);    \
            acc2[1] += __builtin_amdgcn_cvt_pk_f32_fp8((int)wv[u], true);     \
        }                                                                     \
    }

    if (useL) {
        const i32x4* ipL = (const i32x4*)&sIdx[local];
        AGG_LOOP(ipL)
    } else {
        const i32x4* ipG = (const i32x4*)(csr_pad + beg);
        AGG_LOOP(ipG)
    }
#undef AGG_LOOP

    float acc[4] = {acc2[0][0], acc2[0][1], acc2[1][0], acc2[1][1]};
    float invdeg = 1.0f / fmaxf((float)dg, 1.0f);
    float v[4], ss = 0.f;
#pragma unroll
    for (int k = 0; k < 4; ++k) {
        v[k] = fmaxf(fmaf(acc[k], invdeg, h[k]), 0.f);
        ss += v[k] * v[k];
    }
    // reduce across the 16 r-lanes of this node (masks 1,2,4,8)
    ss += __shfl_xor(ss, 1, 64);
    ss += __shfl_xor(ss, 2, 64);
    ss += __shfl_xor(ss, 4, 64);
    ss += __shfl_xor(ss, 8, 64);
    float rs = 1.0f / (sqrtf(ss) + EPS);

    if constexpr (!MLP) {
        // stage normalized row as bf16 into LDS (A-operand of next GEMM)
        unsigned short* ap = &sA[sn * 80 + r * 4];
#pragma unroll
        for (int k = 0; k < 4; ++k) ap[k] = f2bf(v[k] * rs);
        __syncthreads();
        // dual GEMM: wave wv_ covers (mat = wv_>>1, t-pair = (wv_&1)*2)
        int lane = threadIdx.x & 63;
        int wv_  = threadIdx.x >> 6;
        int m    = lane & 15;
        int quad = lane >> 4;
        const short8* pB = (const short8*)((wv_ < 2) ? pS : pN);
        int t0 = (wv_ & 1) * 2;
        f32x4 gacc[2];
        gacc[0] = (f32x4){0.f, 0.f, 0.f, 0.f};
        gacc[1] = (f32x4){0.f, 0.f, 0.f, 0.f};
#pragma unroll
        for (int c = 0; c < 2; ++c) {
            short8 a = *(const short8*)&sA[m * 80 + quad * 8 + c * 32];
#pragma unroll
            for (int tt = 0; tt < 2; ++tt) {
                short8 b = pB[(c * 4 + t0 + tt) * 64 + lane];
                gacc[tt] = __builtin_amdgcn_mfma_f32_16x16x32_bf16(a, b, gacc[tt], 0, 0, 0);
            }
        }
        int row0 = blockIdx.x * 16 + quad * 4;
#pragma unroll
        for (int tt = 0; tt < 2; ++tt) {
            int col = (t0 + tt) * 16 + m;
#pragma unroll
            for (int rr = 0; rr < 4; ++rr) {
                size_t o = (size_t)(row0 + rr) * HID + col;
                if (wv_ < 2) hs2[o]  = gacc[tt][rr];
                else         hnq2[o] = f2fp8(gacc[tt][rr]);
            }
        }
    } else {
#pragma unroll
        for (int k = 0; k < 4; ++k) sH[sn * 68 + r * 4 + k] = v[k] * rs;
        __syncthreads();
        // per node: 16 threads x 2 columns of the 64x32 MLP
        int c0 = r * 2;
        float y0 = sB1[c0], y1 = sB1[c0 + 1];
        const float* hrow2 = &sH[sn * 68];
#pragma unroll 8
        for (int k = 0; k < HID; ++k) {
            float hv = hrow2[k];
            y0 = fmaf(hv, sW1[k * 32 + c0], y0);
            y1 = fmaf(hv, sW1[k * 32 + c0 + 1], y1);
        }
        float p = fmaxf(y0, 0.f) * sW2[c0] + fmaxf(y1, 0.f) * sW2[c0 + 1];
        p += __shfl_xor(p, 1, 64);
        p += __shfl_xor(p, 2, 64);
        p += __shfl_xor(p, 4, 64);
        p += __shfl_xor(p, 8, 64);
        if (r == 0) out[node] = 1.0f / (1.0f + __expf(-(p + mb2[0])));
    }
}

extern "C" void kernel_launch(void* const* d_in, const int* in_sizes, int n_in,
                              void* d_out, int out_size, void* d_ws, size_t ws_size,
                              hipStream_t stream) {
    const float* x   = (const float*)d_in[0];
    const int*   ei  = (const int*)d_in[1];
    const float* w0s = (const float*)d_in[2];
    const float* w0n = (const float*)d_in[3];
    const float* w1s = (const float*)d_in[4];
    const float* w1n = (const float*)d_in[5];
    const float* w2s = (const float*)d_in[6];
    const float* w2n = (const float*)d_in[7];
    const float* mw1 = (const float*)d_in[8];
    const float* mb1 = (const float*)d_in[9];
    const float* mw2 = (const float*)d_in[10];
    const float* mb2 = (const float*)d_in[11];
    float*       out = (float*)d_out;

    // ---- workspace layout (all sections 16B aligned) ----
    int* pbeg        = (int*)d_ws;               // 50048
    int* rdeg        = pbeg + 50048;             // 50048
    int* bc          = rdeg + 50048;             // NBLK*NB = 152881 (pad 153600)
    int* bucketBase  = bc + 153600;              // 512
    int* bucketTot   = bucketBase + 512;         // 512
    int* gcount      = bucketTot + 512;          // 64
    unsigned int* bucketPacked = (unsigned int*)(gcount + 64);    // 1.6M uint
    int* csr_pad     = (int*)(bucketPacked + N_EDGES);            // NB*PBKT = 3,203,072
    const size_t NH = (size_t)N_NODES * HID;
    float*          hsA  = (float*)(csr_pad + NB * PBKT);         // NH f32
    unsigned char*  hnqA = (unsigned char*)(hsA + NH);            // NH fp8 + 64B zero row
    float*          hsB  = (float*)(hnqA + NH + 64);              // NH f32
    unsigned char*  hnqB = (unsigned char*)(hsB + NH);            // NH fp8 + 64B zero row
    unsigned short* p0S = (unsigned short*)(hnqB + NH + 64);      // 128*64
    unsigned short* p0N = p0S + IN_DIM * HID;
    unsigned short* p1S = p0N + IN_DIM * HID;    // 64*64
    unsigned short* p1N = p1S + HID * HID;
    unsigned short* p2S = p1N + HID * HID;
    unsigned short* p2N = p2S + HID * HID;
    // total ~55 MB

    const int nodeGrid = N_NODES / 16;           // 3125 blocks: 16 nodes/block, 4 waves

    // ---- build chain (4 dispatches; gemm0 overlapped with col_sumfix) ----
    bucket_count_pack<<<NBLK + 8, 256, 0, stream>>>(
        ei, bc, w0s, w0n, w1s, w1n, w2s, w2n,
        p0S, p0N, p1S, p1N, p2S, p2N, hnqA, hnqB, gcount);
    col_sumfix_gemm0<<<NB + GEMM0G, 256, 0, stream>>>(
        bc, bucketBase, bucketTot, gcount, x, p0S, p0N, hsA, hnqA);
    bucket_scatter<<<NBLK, 256, 0, stream>>>(ei, bc, bucketPacked);
    node_scan_scatter_pad<<<NB, 256, 0, stream>>>(bucketPacked, bucketBase, bucketTot,
                                                  pbeg, rdeg, csr_pad);

    // ---- layer 0 aggregate + fused layer-1 GEMM ----
    agg_update<false><<<nodeGrid, 256, 0, stream>>>(
        pbeg, rdeg, csr_pad, hnqA, hsA, p1S, p1N, hsB, hnqB,
        nullptr, nullptr, nullptr, nullptr, nullptr);

    // ---- layer 1 aggregate + fused layer-2 GEMM ----
    agg_update<false><<<nodeGrid, 256, 0, stream>>>(
        pbeg, rdeg, csr_pad, hnqB, hsB, p2S, p2N, hsA, hnqA,
        nullptr, nullptr, nullptr, nullptr, nullptr);

    // ---- layer 2 aggregate + fused MLP head ----
    agg_update<true><<<nodeGrid, 256, 0, stream>>>(
        pbeg, rdeg, csr_pad, hnqA, hsA, nullptr, nullptr, nullptr, nullptr,
        mw1, mb1, mw2, mb2, out);
}

// Round 14
// 203.455 us; speedup vs baseline: 1.0328x; 1.0328x over previous
//
#include <hip/hip_runtime.h>
#include <hip/hip_bf16.h>
#include <math.h>

#define N_NODES 50000
#define N_EDGES 1600000
#define IN_DIM  128
#define HID     64
#define EPB     4096   // edges per sort block
#define NBLK    391    // ceil(N_EDGES / EPB)
#define NB      391    // ceil(N_NODES / 128) buckets of 128 nodes
#define CAP     8192   // LDS staging capacity (edges/bucket; mean 4092)
#define PBKT    8192   // padded per-bucket arena in csr_pad (max ~5300 used)
#define GEMM0G  782    // layer-0 GEMM blocks
static constexpr float EPS = 1e-6f;

typedef __attribute__((ext_vector_type(8))) short          short8;   // 8 bf16
typedef __attribute__((ext_vector_type(4))) int            i32x4;
typedef __attribute__((ext_vector_type(4))) float          f32x4;
typedef __attribute__((ext_vector_type(2))) float          f32x2;

__device__ __forceinline__ unsigned short f2bf(float f) {   // round-nearest-even
    union { float f; unsigned int i; } c; c.f = f;
    unsigned int r = c.i + 0x7FFFu + ((c.i >> 16) & 1u);
    return (unsigned short)(r >> 16);
}
__device__ __forceinline__ unsigned char f2fp8(float f) {   // OCP e4m3, HW cvt
    int p = __builtin_amdgcn_cvt_pk_fp8_f32(f, f, 0, false);
    return (unsigned char)(p & 0xff);
}

// ==== weight packing =========================================================

template <int K>
__device__ __forceinline__ void pack_body(const float* __restrict__ wS,
                                          const float* __restrict__ wN,
                                          unsigned short* __restrict__ pS,
                                          unsigned short* __restrict__ pN, int blk) {
    constexpr int NSLOT = (K / 32) * 4 * 64;
    int slot = blk * 256 + (int)threadIdx.x;
    if (slot >= NSLOT) return;
    int lane = slot & 63;
    int ct   = slot >> 6;
    int t    = ct & 3;
    int c    = ct >> 2;
    int m    = lane & 15;
    int quad = lane >> 4;
    int col  = t * 16 + m;
#pragma unroll
    for (int j = 0; j < 8; ++j) {
        int k = c * 32 + quad * 8 + j;
        pS[slot * 8 + j] = f2bf(wS[k * 64 + col]);
        pN[slot * 8 + j] = f2bf(wN[k * 64 + col]);
    }
}

// ==== dual GEMM body (layer 0) ===============================================
template <int K, bool F32IN>
__device__ __forceinline__ void gemm_body(
    const void* __restrict__ Av,
    const unsigned short* __restrict__ pS,
    const unsigned short* __restrict__ pN,
    float* __restrict__ hs, unsigned char* __restrict__ hnq, int blk) {
    constexpr int NC = K / 32;
    int lane = threadIdx.x & 63;
    int wv   = threadIdx.x >> 6;
    int tile = blk * 4 + wv;
    if (tile >= N_NODES / 16) return;
    int m    = lane & 15;
    int quad = lane >> 4;

    const short8* pSf = (const short8*)pS;
    const short8* pNf = (const short8*)pN;

    f32x4 accS[4], accN[4];
#pragma unroll
    for (int t = 0; t < 4; ++t) {
        accS[t] = (f32x4){0.f, 0.f, 0.f, 0.f};
        accN[t] = (f32x4){0.f, 0.f, 0.f, 0.f};
    }
#pragma unroll
    for (int c = 0; c < NC; ++c) {
        short8 a;
        if constexpr (F32IN) {
            const float* Af = (const float*)Av + ((size_t)tile * 16 + m) * K + quad * 8 + c * 32;
            f32x4 a0 = *(const f32x4*)Af;
            f32x4 a1 = *(const f32x4*)(Af + 4);
#pragma unroll
            for (int k = 0; k < 4; ++k) a[k]     = (short)f2bf(a0[k]);
#pragma unroll
            for (int k = 0; k < 4; ++k) a[k + 4] = (short)f2bf(a1[k]);
        } else {
            const short8* Af = (const short8*)((const unsigned short*)Av +
                               ((size_t)tile * 16 + m) * K + quad * 8);
            a = Af[c * 4];
        }
#pragma unroll
        for (int t = 0; t < 4; ++t) {
            short8 bs = pSf[(c * 4 + t) * 64 + lane];
            short8 bn = pNf[(c * 4 + t) * 64 + lane];
            accS[t] = __builtin_amdgcn_mfma_f32_16x16x32_bf16(a, bs, accS[t], 0, 0, 0);
            accN[t] = __builtin_amdgcn_mfma_f32_16x16x32_bf16(a, bn, accN[t], 0, 0, 0);
        }
    }
    int row0 = tile * 16 + quad * 4;
#pragma unroll
    for (int t = 0; t < 4; ++t) {
#pragma unroll
        for (int r = 0; r < 4; ++r) {
            size_t o = (size_t)(row0 + r) * HID + t * 16 + m;
            hs[o]  = accS[t][r];
            hnq[o] = f2fp8(accN[t][r]);
        }
    }
}

// ==== kernel 1: histogram count ∥ weight pack ================================
__global__ __launch_bounds__(256) void bucket_count_pack(
    const int* __restrict__ ei, int* __restrict__ bc,
    const float* __restrict__ w0s, const float* __restrict__ w0n,
    const float* __restrict__ w1s, const float* __restrict__ w1n,
    const float* __restrict__ w2s, const float* __restrict__ w2n,
    unsigned short* __restrict__ p0S, unsigned short* __restrict__ p0N,
    unsigned short* __restrict__ p1S, unsigned short* __restrict__ p1N,
    unsigned short* __restrict__ p2S, unsigned short* __restrict__ p2N,
    unsigned char* __restrict__ hnqA, unsigned char* __restrict__ hnqB,
    int* __restrict__ gcount) {
    if (blockIdx.x >= NBLK) {
        int blk = blockIdx.x - NBLK;
        if (blk == 7) {
            if (threadIdx.x >= 128 && threadIdx.x < 144)
                ((unsigned int*)(hnqA + (size_t)N_NODES * HID))[threadIdx.x - 128] = 0u;
            if (threadIdx.x >= 144 && threadIdx.x < 160)
                ((unsigned int*)(hnqB + (size_t)N_NODES * HID))[threadIdx.x - 144] = 0u;
            if (threadIdx.x == 160) gcount[0] = 0;
        }
        if (blk < 4)      pack_body<IN_DIM>(w0s, w0n, p0S, p0N, blk);
        else if (blk < 6) pack_body<HID>(w1s, w1n, p1S, p1N, blk - 4);
        else              pack_body<HID>(w2s, w2n, p2S, p2N, blk - 6);
        return;
    }
    __shared__ int hist[NB];
    for (int i = threadIdx.x; i < NB; i += 256) hist[i] = 0;
    __syncthreads();
    int base = blockIdx.x * EPB;
    int lim  = min(EPB, N_EDGES - base);
    for (int i = threadIdx.x; i < lim; i += 256)
        atomicAdd(&hist[ei[N_EDGES + base + i] >> 7], 1);
    __syncthreads();
    for (int b = threadIdx.x; b < NB; b += 256)
        bc[blockIdx.x * NB + b] = hist[b];
}

// ==== kernel 2: fused col_sum + base-alloc + in-row prefix ∥ layer-0 GEMM ====
__global__ __launch_bounds__(256) void col_sumfix_gemm0(
    int* __restrict__ bc, int* __restrict__ bucketBase, int* __restrict__ bucketTot,
    int* __restrict__ gcount,
    const float* __restrict__ x,
    const unsigned short* __restrict__ p0S, const unsigned short* __restrict__ p0N,
    float* __restrict__ hs, unsigned char* __restrict__ hnq) {
    if (blockIdx.x >= NB) {
        gemm_body<IN_DIM, true>(x, p0S, p0N, hs, hnq, blockIdx.x - NB);
        return;
    }
    __shared__ int vals[NBLK];
    int b = blockIdx.x;
    for (int i = threadIdx.x; i < NBLK; i += 256) vals[i] = bc[i * NB + b];
    __syncthreads();
    if (threadIdx.x < 64) {
        int lane = threadIdx.x;
        int s = 0;
        for (int i = lane; i < NBLK; i += 64) s += vals[i];
#pragma unroll
        for (int off = 32; off >= 1; off >>= 1) s += __shfl_xor(s, off, 64);
        int base = 0;
        if (lane == 0) {
            base = atomicAdd(gcount, s);
            bucketBase[b] = base;
            bucketTot[b]  = s;
        }
        base = __shfl(base, 0, 64);
        int carry = base;
        for (int bs = 0; bs < NBLK; bs += 64) {
            int i = bs + lane;
            int v = (i < NBLK) ? vals[i] : 0;
            int incl = v;
#pragma unroll
            for (int off = 1; off < 64; off <<= 1) {
                int t = __shfl_up(incl, off, 64);
                if (lane >= off) incl += t;
            }
            if (i < NBLK) vals[i] = carry + incl - v;
            carry += __shfl(incl, 63, 64);
        }
    }
    __syncthreads();
    for (int i = threadIdx.x; i < NBLK; i += 256) bc[i * NB + b] = vals[i];
}

// ==== kernel 3: scatter edges into bucket-sorted order =======================
__global__ __launch_bounds__(256) void bucket_scatter(const int* __restrict__ ei,
                                                      const int* __restrict__ bc,
                                                      unsigned int* __restrict__ bucketPacked) {
    __shared__ int cur[NB];
    for (int b = threadIdx.x; b < NB; b += 256)
        cur[b] = bc[blockIdx.x * NB + b];
    __syncthreads();
    int base = blockIdx.x * EPB;
    int lim  = min(EPB, N_EDGES - base);
    for (int i = threadIdx.x; i < lim; i += 256) {
        int s = ei[base + i];
        int d = ei[N_EDGES + base + i];
        int pos = atomicAdd(&cur[d >> 7], 1);
        bucketPacked[pos] = ((unsigned int)s << 7) | (unsigned int)(d & 127);
    }
}

// ==== kernel 4: per-bucket degree count -> padded scan -> pbeg/rdeg ->
// sentinel fill -> local scatter. csr_pad entries are PRE-SHIFTED byte
// offsets (src*64) so the gather loop needs no per-edge shift.
__global__ __launch_bounds__(256) void node_scan_scatter_pad(
    const unsigned int* __restrict__ bucketPacked,
    const int* __restrict__ bucketBase, const int* __restrict__ bucketTot,
    int* __restrict__ pbeg, int* __restrict__ rdeg, int* __restrict__ csr_pad) {
    __shared__ int cnt[128];
    __shared__ int half0;
    __shared__ unsigned int stage[CAP];
    int tid = threadIdx.x;
    if (tid < 128) cnt[tid] = 0;
    __syncthreads();
    int beg = bucketBase[blockIdx.x];
    int n   = bucketTot[blockIdx.x];
    for (int i = tid; i < n; i += 256) {
        unsigned int e = bucketPacked[beg + i];
        if (i < CAP) stage[i] = e;
        atomicAdd(&cnt[e & 127], 1);
    }
    __syncthreads();
    int lane = tid & 63;
    int v    = (tid < 128) ? cnt[tid] : 0;   // raw degree of node tid
    int vp   = (v + 7) & ~7;                 // padded degree
    int incl = vp;
#pragma unroll
    for (int off = 1; off < 64; off <<= 1) {
        int t = __shfl_up(incl, off, 64);
        if (lane >= off) incl += t;
    }
    if (tid == 63) half0 = incl;
    __syncthreads();
    int start = blockIdx.x * PBKT + ((tid >= 64 && tid < 128) ? half0 : 0) + incl - vp;
    int node  = blockIdx.x * 128 + tid;
    if (tid < 128 && node < N_NODES) {
        pbeg[node] = start;
        rdeg[node] = v;
        for (int j = v; j < vp; ++j) csr_pad[start + j] = N_NODES << 6;   // sentinels
        cnt[tid] = start;   // becomes the scatter cursor
    }
    __syncthreads();
    for (int i = tid; i < n; i += 256) {
        unsigned int e = (i < CAP) ? stage[i] : bucketPacked[beg + i];
        int pos = atomicAdd(&cnt[e & 127], 1);
        csr_pad[pos] = (int)((e >> 7) << 6);   // pre-shifted byte offset
    }
}

// ==== fused gather-aggregate + update + NEXT-LAYER dual GEMM (or MLP head) ===
// 4 nodes per wave, 16 lanes per node (sn = tid>>4, r = lane&15 -> 4B chunk).
// Maskless main loop (padded CSR, pre-shifted byte-offset entries); hs row
// prefetched before the gather loop. !MLP: block's 16 nodes = one GEMM tile
// -> next layer's hs2/hnq2.
template <bool MLP>
__global__ __launch_bounds__(256) void agg_update(
    const int* __restrict__ pbeg, const int* __restrict__ rdeg,
    const int* __restrict__ csr_pad,
    const unsigned char* __restrict__ hnq, const float* __restrict__ hs,
    const unsigned short* __restrict__ pS, const unsigned short* __restrict__ pN,
    float* __restrict__ hs2, unsigned char* __restrict__ hnq2,
    const float* __restrict__ mw1, const float* __restrict__ mb1,
    const float* __restrict__ mw2, const float* __restrict__ mb2,
    float* __restrict__ out) {
    __shared__ unsigned short sA[MLP ? 1 : 16 * 80];   // 16 nodes x 64 bf16, stride 80
    __shared__ float sW1[MLP ? HID * 32 : 1];
    __shared__ float sW2[MLP ? 32 : 1];
    __shared__ float sB1[MLP ? 32 : 1];
    __shared__ float sH[MLP ? 16 * 68 : 1];
    if (MLP) {
        for (int i = threadIdx.x; i < HID * 32; i += 256) sW1[i] = mw1[i];
        if (threadIdx.x < 32) { sW2[threadIdx.x] = mw2[threadIdx.x]; sB1[threadIdx.x] = mb1[threadIdx.x]; }
        __syncthreads();
    }
    int sn   = threadIdx.x >> 4;          // node slot within block, 0..15
    int r    = threadIdx.x & 15;          // 4B chunk of the 64B row
    int node = blockIdx.x * 16 + sn;      // grid = 3125 -> exactly N_NODES
    int beg  = pbeg[node];
    int dg   = rdeg[node];
    f32x4 h  = *(const f32x4*)(hs + (size_t)node * HID + r * 4);   // prefetch
    int nbat = (dg + 7) >> 3;
    const i32x4* ip = (const i32x4*)(csr_pad + beg);
    const unsigned char* hnqr = hnq + r * 4;

    f32x2 acc2[2];
    acc2[0] = (f32x2){0.f, 0.f};
    acc2[1] = (f32x2){0.f, 0.f};

#pragma unroll 2
    for (int t = 0; t < nbat; ++t) {
        i32x4 a = ip[2 * t];
        i32x4 b = ip[2 * t + 1];
        unsigned wv[8];
#pragma unroll
        for (int u = 0; u < 4; ++u)
            wv[u]     = *(const unsigned*)(hnqr + (unsigned)a[u]);
#pragma unroll
        for (int u = 0; u < 4; ++u)
            wv[u + 4] = *(const unsigned*)(hnqr + (unsigned)b[u]);
#pragma unroll
        for (int u = 0; u < 8; ++u) {
#if __has_builtin(__builtin_amdgcn_cvt_pk_f32_fp8)
            acc2[0] += __builtin_amdgcn_cvt_pk_f32_fp8((int)wv[u], false);
            acc2[1] += __builtin_amdgcn_cvt_pk_f32_fp8((int)wv[u], true);
#else
            acc2[0] += (f32x2){__builtin_amdgcn_cvt_f32_fp8((int)wv[u], 0),
                               __builtin_amdgcn_cvt_f32_fp8((int)wv[u], 1)};
            acc2[1] += (f32x2){__builtin_amdgcn_cvt_f32_fp8((int)wv[u], 2),
                               __builtin_amdgcn_cvt_f32_fp8((int)wv[u], 3)};
#endif
        }
    }

    float acc[4] = {acc2[0][0], acc2[0][1], acc2[1][0], acc2[1][1]};
    float invdeg = 1.0f / fmaxf((float)dg, 1.0f);
    float v[4], ss = 0.f;
#pragma unroll
    for (int k = 0; k < 4; ++k) {
        v[k] = fmaxf(fmaf(acc[k], invdeg, h[k]), 0.f);
        ss += v[k] * v[k];
    }
    // reduce across the 16 r-lanes of this node (masks 1,2,4,8)
    ss += __shfl_xor(ss, 1, 64);
    ss += __shfl_xor(ss, 2, 64);
    ss += __shfl_xor(ss, 4, 64);
    ss += __shfl_xor(ss, 8, 64);
    float rs = 1.0f / (sqrtf(ss) + EPS);

    if constexpr (!MLP) {
        // stage normalized row as bf16 into LDS (A-operand of next GEMM)
        unsigned short* ap = &sA[sn * 80 + r * 4];
#pragma unroll
        for (int k = 0; k < 4; ++k) ap[k] = f2bf(v[k] * rs);
        __syncthreads();
        // dual GEMM: wave wv_ covers (mat = wv_>>1, t-pair = (wv_&1)*2)
        int lane = threadIdx.x & 63;
        int wv_  = threadIdx.x >> 6;
        int m    = lane & 15;
        int quad = lane >> 4;
        const short8* pB = (const short8*)((wv_ < 2) ? pS : pN);
        int t0 = (wv_ & 1) * 2;
        f32x4 gacc[2];
        gacc[0] = (f32x4){0.f, 0.f, 0.f, 0.f};
        gacc[1] = (f32x4){0.f, 0.f, 0.f, 0.f};
#pragma unroll
        for (int c = 0; c < 2; ++c) {
            short8 a = *(const short8*)&sA[m * 80 + quad * 8 + c * 32];
#pragma unroll
            for (int tt = 0; tt < 2; ++tt) {
                short8 b = pB[(c * 4 + t0 + tt) * 64 + lane];
                gacc[tt] = __builtin_amdgcn_mfma_f32_16x16x32_bf16(a, b, gacc[tt], 0, 0, 0);
            }
        }
        int row0 = blockIdx.x * 16 + quad * 4;
#pragma unroll
        for (int tt = 0; tt < 2; ++tt) {
            int col = (t0 + tt) * 16 + m;
#pragma unroll
            for (int rr = 0; rr < 4; ++rr) {
                size_t o = (size_t)(row0 + rr) * HID + col;
                if (wv_ < 2) hs2[o]  = gacc[tt][rr];
                else         hnq2[o] = f2fp8(gacc[tt][rr]);
            }
        }
    } else {
#pragma unroll
        for (int k = 0; k < 4; ++k) sH[sn * 68 + r * 4 + k] = v[k] * rs;
        __syncthreads();
        // per node: 16 threads x 2 columns of the 64x32 MLP
        int c0 = r * 2;
        float y0 = sB1[c0], y1 = sB1[c0 + 1];
        const float* hrow2 = &sH[sn * 68];
#pragma unroll 8
        for (int k = 0; k < HID; ++k) {
            float hv = hrow2[k];
            y0 = fmaf(hv, sW1[k * 32 + c0], y0);
            y1 = fmaf(hv, sW1[k * 32 + c0 + 1], y1);
        }
        float p = fmaxf(y0, 0.f) * sW2[c0] + fmaxf(y1, 0.f) * sW2[c0 + 1];
        p += __shfl_xor(p, 1, 64);
        p += __shfl_xor(p, 2, 64);
        p += __shfl_xor(p, 4, 64);
        p += __shfl_xor(p, 8, 64);
        if (r == 0) out[node] = 1.0f / (1.0f + __expf(-(p + mb2[0])));
    }
}

extern "C" void kernel_launch(void* const* d_in, const int* in_sizes, int n_in,
                              void* d_out, int out_size, void* d_ws, size_t ws_size,
                              hipStream_t stream) {
    const float* x   = (const float*)d_in[0];
    const int*   ei  = (const int*)d_in[1];
    const float* w0s = (const float*)d_in[2];
    const float* w0n = (const float*)d_in[3];
    const float* w1s = (const float*)d_in[4];
    const float* w1n = (const float*)d_in[5];
    const float* w2s = (const float*)d_in[6];
    const float* w2n = (const float*)d_in[7];
    const float* mw1 = (const float*)d_in[8];
    const float* mb1 = (const float*)d_in[9];
    const float* mw2 = (const float*)d_in[10];
    const float* mb2 = (const float*)d_in[11];
    float*       out = (float*)d_out;

    // ---- workspace layout (all sections 16B aligned) ----
    int* pbeg        = (int*)d_ws;               // 50048
    int* rdeg        = pbeg + 50048;             // 50048
    int* bc          = rdeg + 50048;             // NBLK*NB = 152881 (pad 153600)
    int* bucketBase  = bc + 153600;              // 512
    int* bucketTot   = bucketBase + 512;         // 512
    int* gcount      = bucketTot + 512;          // 64
    unsigned int* bucketPacked = (unsigned int*)(gcount + 64);    // 1.6M uint
    int* csr_pad     = (int*)(bucketPacked + N_EDGES);            // NB*PBKT = 3,203,072
    const size_t NH = (size_t)N_NODES * HID;
    float*          hsA  = (float*)(csr_pad + NB * PBKT);         // NH f32
    unsigned char*  hnqA = (unsigned char*)(hsA + NH);            // NH fp8 + 64B zero row
    float*          hsB  = (float*)(hnqA + NH + 64);              // NH f32
    unsigned char*  hnqB = (unsigned char*)(hsB + NH);            // NH fp8 + 64B zero row
    unsigned short* p0S = (unsigned short*)(hnqB + NH + 64);      // 128*64
    unsigned short* p0N = p0S + IN_DIM * HID;
    unsigned short* p1S = p0N + IN_DIM * HID;    // 64*64
    unsigned short* p1N = p1S + HID * HID;
    unsigned short* p2S = p1N + HID * HID;
    unsigned short* p2N = p2S + HID * HID;
    // total ~55 MB

    const int nodeGrid = N_NODES / 16;           // 3125 blocks: 16 nodes/block, 4 waves

    // ---- build chain (4 dispatches; gemm0 overlapped with col_sumfix) ----
    bucket_count_pack<<<NBLK + 8, 256, 0, stream>>>(
        ei, bc, w0s, w0n, w1s, w1n, w2s, w2n,
        p0S, p0N, p1S, p1N, p2S, p2N, hnqA, hnqB, gcount);
    col_sumfix_gemm0<<<NB + GEMM0G, 256, 0, stream>>>(
        bc, bucketBase, bucketTot, gcount, x, p0S, p0N, hsA, hnqA);
    bucket_scatter<<<NBLK, 256, 0, stream>>>(ei, bc, bucketPacked);
    node_scan_scatter_pad<<<NB, 256, 0, stream>>>(bucketPacked, bucketBase, bucketTot,
                                                  pbeg, rdeg, csr_pad);

    // ---- layer 0 aggregate + fused layer-1 GEMM ----
    agg_update<false><<<nodeGrid, 256, 0, stream>>>(
        pbeg, rdeg, csr_pad, hnqA, hsA, p1S, p1N, hsB, hnqB,
        nullptr, nullptr, nullptr, nullptr, nullptr);

    // ---- layer 1 aggregate + fused layer-2 GEMM ----
    agg_update<false><<<nodeGrid, 256, 0, stream>>>(
        pbeg, rdeg, csr_pad, hnqB, hsB, p2S, p2N, hsA, hnqA,
        nullptr, nullptr, nullptr, nullptr, nullptr);

    // ---- layer 2 aggregate + fused MLP head ----
    agg_update<true><<<nodeGrid, 256, 0, stream>>>(
        pbeg, rdeg, csr_pad, hnqA, hsA, nullptr, nullptr, nullptr, nullptr,
        mw1, mb1, mw2, mb2, out);
}